// Round 16
// baseline (175.983 us; speedup 1.0000x reference)
//
#include <hip/hip_runtime.h>
#include <hip/hip_bf16.h>
#include <stdint.h>

// Problem dims
#define B_DIM 4096
#define NFEATS 2048
#define NTAGS 300
#define NTAGSP 320
#define RIN 512
#define RHID 512
#define HIDD 512
#define KCAT 1536

typedef __attribute__((ext_vector_type(8))) short short8;
typedef __attribute__((ext_vector_type(8))) unsigned short ushort8;
typedef __attribute__((ext_vector_type(4))) float f32x4;

typedef __attribute__((address_space(3))) unsigned int lds_u32_t;
typedef __attribute__((address_space(1))) const unsigned int glb_u32_t;

__device__ __forceinline__ unsigned short f2bf(float f) {
  union { float f; unsigned u; } x; x.f = f;
  unsigned r = (x.u + 0x7fffu + ((x.u >> 16) & 1u)) >> 16;
  return (unsigned short)r;
}
__device__ __forceinline__ float bf2f(unsigned short u) {
  union { unsigned u; float f; } x; x.u = ((unsigned)u) << 16;
  return x.f;
}

__device__ __forceinline__ void gl2lds16(const void* g, void* l) {
  __builtin_amdgcn_global_load_lds((glb_u32_t*)g, (lds_u32_t*)l, 16, 0, 0);
}

__device__ __forceinline__ void sbar() {
  asm volatile("" ::: "memory");
  __builtin_amdgcn_s_barrier();
  asm volatile("" ::: "memory");
}
#define CB()       asm volatile("" ::: "memory")            // pin memory-op groups
#define SCHEDB()   __builtin_amdgcn_sched_barrier(0)        // pin non-memory ops (MFMA)
#define VMCNT4()   asm volatile("s_waitcnt vmcnt(4)" ::: "memory")
#define VMCNT2()   asm volatile("s_waitcnt vmcnt(2)" ::: "memory")
#define VMCNT0()   asm volatile("s_waitcnt vmcnt(0)" ::: "memory")
#define LGKMCNT0() asm volatile("s_waitcnt lgkmcnt(0)" ::: "memory")

// ---------------- merged prep: activation convert + weight transpose ----------------
struct TD { const float* src; unsigned short* dst; int K; int dstLd; int dstOff; int kx0; };
struct TP { TD d[9]; };

__global__ void prep_all(TP tp,
                         const float* __restrict__ v, const float* __restrict__ x,
                         const float* __restrict__ h, const float* __restrict__ s,
                         unsigned short* __restrict__ vb, unsigned short* __restrict__ xb,
                         unsigned short* __restrict__ hb, unsigned short* __restrict__ sb) {
  __shared__ float t[64][65];
  int bid = blockIdx.x;
  if (bid < 2048) {
    int seg = bid >> 9;
    int inner = bid & 511;
    const float* src; unsigned short* dst; int sc, dc;
    if (seg == 0)      { src = v; dst = vb; sc = NFEATS; dc = NFEATS; }
    else if (seg == 1) { src = x; dst = xb; sc = RIN;    dc = RIN; }
    else if (seg == 2) { src = h; dst = hb; sc = RHID;   dc = RHID; }
    else               { src = s; dst = sb; sc = NTAGS;  dc = NTAGSP; }
    int cpr = dc >> 3;
    long nch = (long)B_DIM * cpr;
    for (long i = (long)inner * blockDim.x + threadIdx.x; i < nch;
         i += (long)512 * blockDim.x) {
      int r = (int)(i / cpr);
      int c0 = (int)(i - (long)r * cpr) << 3;
      const float* sp = src + (long)r * sc + c0;
      ushort8 o;
#pragma unroll
      for (int j = 0; j < 8; ++j) {
        float f = (c0 + j < sc) ? sp[j] : 0.f;
        o[j] = f2bf(f);
      }
      *(ushort8*)(dst + (i << 3)) = o;
    }
  } else {
    int tb = bid - 2048;                 // 0..2783 = 87*8*4 - 1
    int bz = tb / (87 * 8);
    int rem = tb - bz * (87 * 8);
    int by = rem / 87;
    int bx = rem - by * 87;
    int m = 0;
#pragma unroll
    for (int i = 1; i < 9; ++i)
      if (bx >= tp.d[i].kx0) m = i;
    TD td = tp.d[m];
    const float* sp = td.src + (long)bz * td.K * 512;
    unsigned short* d = td.dst + (long)bz * 512 * td.dstLd;
    int k0 = (bx - td.kx0) * 64, n0 = by * 64;
    int tx = threadIdx.x & 63, ty = threadIdx.x >> 6;   // ty 0..3
#pragma unroll
    for (int p = 0; p < 16; ++p) {
      int kr = p * 4 + ty;
      int k = k0 + kr;
      t[kr][tx] = (k < td.K) ? sp[(long)k * 512 + n0 + tx] : 0.f;
    }
    __syncthreads();
#pragma unroll
    for (int p = 0; p < 16; ++p) {
      int nr = p * 4 + ty;
      d[(long)(n0 + nr) * td.dstLd + td.dstOff + k0 + tx] = f2bf(t[tx][nr]);
    }
  }
}

// ================= (64*MFR)x256 GEMM core — triple-A, 1 barrier per K-tile =================
// Evolution of the r8 core: A is TRIPLE-buffered so stage A(g+2) targets buffer
// (g+2)%3 whose last readers were tile g-1 — no same-tile reader/writer conflict,
// so the mid-tile drain+barrier (r8's B1) is DELETED. All staging (A and B) sits
// in the open interval with the reads and all 4 MFMA quadrants; one
// LGKMCNT0+SCHEDB+vmcnt+barrier per K-tile. Safety: every tile's ds_reads are
// force-drained (LGKMCNT0, SCHEDB-pinned per rule #18) before its end barrier;
// all writes in tile g target buffers whose readers were tile g-1 (A: %3;
// B: double-buffer, same argument as r5..r15). vmcnt FIFO ledger:
//   prologue: A(0)[4|2] B(0)[4] A(1)[4|2] -> vmcnt(4|2) leaves A(1)
//   tile g:   issue B(g+1)[4] A(g+2)[4|2] -> vmcnt(4|2) drains A(g+1),B(g+1),
//             leaves A(g+2);  tail (g+2>=nt): vmcnt(0)
// LDS: MFR=4: 3*32K A + 2*32K B = 160 KB (full CU LDS; AITER fmha precedent).

__device__ __forceinline__ void stage_half(const unsigned short* mat, int ld,
                                           int gRow0, int k0, char* ldsHalf,
                                           int rl0, int scb, int dstoff) {
  const char* s0 = (const char*)(mat + (long)(gRow0 + rl0) * ld + k0) + scb;
  const char* s1 = (const char*)(mat + (long)(gRow0 + 64 + rl0) * ld + k0) + scb;
  gl2lds16(s0, ldsHalf + dstoff);
  gl2lds16(s1, ldsHalf + 8192 + dstoff);
}

template<int MFR>
__device__ __forceinline__ void mfma_q(f32x4 (&acc)[2 * MFR][4], int mb, int nb,
                                       const short8 (&af)[MFR][2], const short8 (&bf)[2][2]) {
  __builtin_amdgcn_s_setprio(1);
#pragma unroll
  for (int m = 0; m < MFR; ++m)
#pragma unroll
    for (int n = 0; n < 2; ++n)
#pragma unroll
      for (int kk = 0; kk < 2; ++kk)
        acc[mb + m][nb + n] =
            __builtin_amdgcn_mfma_f32_16x16x32_bf16(af[m][kk], bf[n][kk], acc[mb + m][nb + n], 0, 0, 0);
  __builtin_amdgcn_s_setprio(0);
}

template<int MFR>
__device__ __forceinline__ void gemm8_core(const unsigned short* __restrict__ A, int lda,
                                           const unsigned short* __restrict__ Bm, int ldb,
                                           int nt, int rowBase, int colBase,
                                           char* smem, int tid, f32x4 (&acc)[2 * MFR][4]) {
  constexpr int ATILE = 8192 * MFR;     // bytes per A K-tile (64*MFR rows x 128B)
  char* Ab0 = smem;                      // A tri-buf: 3*ATILE
  char* Bb0 = smem + 3 * ATILE;          // B dbuf: 2*32KB
  int l = tid & 63, w = tid >> 6;
  int wr = w >> 2, wc = w & 3;
  int lr = l & 15, lg = l >> 4;
  int LA = lr * 128 + ((lg * 16) ^ ((lr & 7) << 4));   // swizzled lane read base
  int rl0 = tid >> 3;
  int scb = ((tid & 7) << 4) ^ ((rl0 & 7) << 4);       // inverse-swizzled src col
  int dstoff = (tid & ~63) << 4;                       // wave-uniform LDS base

#pragma unroll
  for (int mi = 0; mi < 2 * MFR; ++mi)
#pragma unroll
    for (int ni = 0; ni < 4; ++ni)
#pragma unroll
      for (int r = 0; r < 4; ++r) acc[mi][ni][r] = 0.f;

  // prologue: A(0)->buf0, B(0)->Bb0, A(1)->buf1; drain A(0)+B(0), leave A(1).
  stage_half(A, lda, rowBase, 0, Ab0, rl0, scb, dstoff);
  if constexpr (MFR == 4) stage_half(A, lda, rowBase + 128, 0, Ab0 + ATILE / 2, rl0, scb, dstoff);
  stage_half(Bm, ldb, colBase, 0, Bb0, rl0, scb, dstoff);
  stage_half(Bm, ldb, colBase + 128, 0, Bb0 + 16384, rl0, scb, dstoff);
  if (nt > 1) {
    stage_half(A, lda, rowBase, 64, Ab0 + ATILE, rl0, scb, dstoff);
    if constexpr (MFR == 4) stage_half(A, lda, rowBase + 128, 64, Ab0 + ATILE + ATILE / 2, rl0, scb, dstoff);
    if constexpr (MFR == 4) { VMCNT4(); } else { VMCNT2(); }
  } else {
    VMCNT0();
  }
  sbar();

  for (int g = 0; g < nt; ++g) {
    int cura = g % 3;
    int curb = g & 1;
    char* Ab = Ab0 + cura * ATILE + wr * (ATILE / 2);
    char* AbN = Ab0 + ((g + 2) % 3) * ATILE;
    char* Bb = Bb0 + curb * 32768 + wc * 8192;
    char* BbN = Bb0 + (curb ^ 1) * 32768;
    short8 a0[MFR][2], a1[MFR][2], b0[2][2], b1[2][2];

    // ---- single open interval: all reads + all staging + 4 MFMA quadrants ----
#pragma unroll
    for (int m = 0; m < MFR; ++m) {
      a0[m][0] = *(const short8*)(Ab + m * 2048 + LA);
      a0[m][1] = *(const short8*)(Ab + m * 2048 + (LA ^ 64));
    }
    CB();
#pragma unroll
    for (int n = 0; n < 2; ++n) {
      b0[n][0] = *(const short8*)(Bb + n * 2048 + LA);
      b0[n][1] = *(const short8*)(Bb + n * 2048 + (LA ^ 64));
    }
    CB();
    if (g + 1 < nt) stage_half(Bm, ldb, colBase, (g + 1) * 64, BbN, rl0, scb, dstoff);
#pragma unroll
    for (int n = 0; n < 2; ++n) {
      b1[n][0] = *(const short8*)(Bb + 4096 + n * 2048 + LA);
      b1[n][1] = *(const short8*)(Bb + 4096 + n * 2048 + (LA ^ 64));
    }
    CB();
    if (g + 1 < nt) stage_half(Bm, ldb, colBase + 128, (g + 1) * 64, BbN + 16384, rl0, scb, dstoff);
#pragma unroll
    for (int m = 0; m < MFR; ++m) {
      a1[m][0] = *(const short8*)(Ab + ATILE / 4 + m * 2048 + LA);
      a1[m][1] = *(const short8*)(Ab + ATILE / 4 + m * 2048 + (LA ^ 64));
    }
    CB();
    if (g + 2 < nt) {
      stage_half(A, lda, rowBase, (g + 2) * 64, AbN, rl0, scb, dstoff);
      if constexpr (MFR == 4)
        stage_half(A, lda, rowBase + 128, (g + 2) * 64, AbN + ATILE / 2, rl0, scb, dstoff);
    }
    CB();
    mfma_q<MFR>(acc, 0, 0, a0, b0);       // compiler inserts precise lgkmcnt waits
    mfma_q<MFR>(acc, 0, 2, a0, b1);
    mfma_q<MFR>(acc, MFR, 2, a1, b1);
    mfma_q<MFR>(acc, MFR, 0, a1, b0);

    LGKMCNT0();                            // all this wave's LDS reads drained
    if (g + 2 < nt) {
      if constexpr (MFR == 4) { VMCNT4(); } else { VMCNT2(); }
    } else if (g + 1 < nt) {
      VMCNT0();
    }
    SCHEDB();                              // pin: nothing crosses the drain point
    sbar();                                // single per-tile barrier
  }
}

// ---------------- GEMM kernels ----------------

// TS = s @ [Cb|Wb|Ub]^T  -> TS[3][4096][2048] bf16  (N=6144, K=320)
__global__ __launch_bounds__(512, 2) void gemm_ts(const unsigned short* __restrict__ sb,
                                                  const unsigned short* __restrict__ SBT,
                                                  unsigned short* __restrict__ TS) {
  extern __shared__ char smem[];
  int tid = threadIdx.x;
  int rowBase = blockIdx.x * 256, colBase = blockIdx.y * 256;
  f32x4 acc[8][4];
  gemm8_core<4>(sb, NTAGSP, SBT, NTAGSP, 5, rowBase, colBase, smem, tid, acc);

  int l = tid & 63, w = tid >> 6, wr = w >> 2, wc = w & 3, lr = l & 15, lg = l >> 4;
  int branch = colBase >> 11;
  unsigned short* TSb = TS + (long)branch * B_DIM * 2048;
#pragma unroll
  for (int mi = 0; mi < 8; ++mi)
#pragma unroll
    for (int ni = 0; ni < 4; ++ni) {
      int colg = (colBase & 2047) + wc * 64 + ni * 16 + lr;
      int row0 = rowBase + wr * 128 + mi * 16 + lg * 4;
#pragma unroll
      for (int r = 0; r < 4; ++r)
        TSb[(long)(row0 + r) * 2048 + colg] = f2bf(acc[mi][ni][r]);
    }
}

// P = (A1 @ B1^T) * TS. All blocks MFR=4 (256^2), 1-D grid, XCD-chunked (r11).
__global__ __launch_bounds__(512, 2) void gemm_bil(
    const unsigned short* __restrict__ vb, const unsigned short* __restrict__ xb,
    const unsigned short* __restrict__ hb,
    const unsigned short* __restrict__ CaT, const unsigned short* __restrict__ WaT,
    const unsigned short* __restrict__ UaT,
    const unsigned short* __restrict__ TS, unsigned short* __restrict__ P) {
  extern __shared__ char smem[];
  int tid = threadIdx.x;
  int bid = blockIdx.x;
  int z, nt, coff, K1;
  const unsigned short *A1, *B1;
  int t;
  if (bid < 128) {
    z = 0; A1 = vb; B1 = CaT; K1 = NFEATS; nt = 32; coff = 512; t = bid;
  } else {
    t = bid - 128;
    z = 1 + (t >> 7); t &= 127;
    A1 = (z == 1) ? xb : hb;
    B1 = (z == 1) ? WaT : UaT;
    K1 = RIN; nt = 8; coff = (z == 1) ? 0 : 1024;
  }
  // XCD-chunked 4x4 mapping (t in 0..127; XCD = bid%8 = t%8 since 128%8==0)
  int gx = t & 7, k = t >> 3;
  int rowBase = ((gx >> 1) * 4 + (k >> 2)) * 256;   // 16 row tiles
  int colBase = ((gx & 1) * 4 + (k & 3)) * 256;     // 8 col tiles

  f32x4 acc[8][4];
  gemm8_core<4>(A1, K1, B1, K1, nt, rowBase, colBase, smem, tid, acc);

  int l = tid & 63, w = tid >> 6, wr = w >> 2, wc = w & 3, lr = l & 15, lg = l >> 4;
  const unsigned short* TSz = TS + (long)z * B_DIM * 2048;
#pragma unroll
  for (int mi = 0; mi < 8; ++mi)
#pragma unroll
    for (int ni = 0; ni < 4; ++ni) {
      int colg = colBase + wc * 64 + ni * 16 + lr;
      int gate = colg >> 9;
      int col = coff + (colg & 511);
      int row0 = rowBase + wr * 128 + mi * 16 + lg * 4;
      unsigned short* Pg = P + (long)gate * B_DIM * KCAT;
#pragma unroll
      for (int r = 0; r < 4; ++r) {
        float ts = bf2f(TSz[(long)(row0 + r) * 2048 + colg]);
        Pg[(long)(row0 + r) * KCAT + col] = f2bf(acc[mi][ni][r] * ts);
      }
    }
}

// logits[g] = P[g] @ Wcat[g]^T + b[g]  (128x256 tiles, MFR=2; bf16 output)
__global__ __launch_bounds__(512, 2) void gemm_lg(const unsigned short* __restrict__ P,
                                                  const unsigned short* __restrict__ WcT,
                                                  const float* __restrict__ bias,
                                                  unsigned short* __restrict__ logits) {
  extern __shared__ char smem[];
  int tid = threadIdx.x;
  int bid = blockIdx.x;
  int gx = bid & 7, k = bid >> 3;           // gx = XCD
  int gate = gx >> 1;
  int rowBase = ((gx & 1) * 16 + (k >> 1)) * 128;   // 32 row tiles of 128
  int colBase = (k & 1) * 256;                      // 2 col tiles
  const unsigned short* Pg = P + (long)gate * B_DIM * KCAT;
  const unsigned short* Wg = WcT + (long)gate * 512 * KCAT;
  f32x4 acc[4][4];
  gemm8_core<2>(Pg, KCAT, Wg, KCAT, KCAT / 64, rowBase, colBase, smem, tid, acc);

  int l = tid & 63, w = tid >> 6, wr = w >> 2, wc = w & 3, lr = l & 15, lg = l >> 4;
  unsigned short* Lg = logits + (long)gate * B_DIM * HIDD;
  const float* bg = bias + gate * HIDD;
#pragma unroll
  for (int mi = 0; mi < 4; ++mi)
#pragma unroll
    for (int ni = 0; ni < 4; ++ni) {
      int col = colBase + wc * 64 + ni * 16 + lr;
      float bv = bg[col];
      int row0 = rowBase + wr * 64 + mi * 16 + lg * 4;
#pragma unroll
      for (int r = 0; r < 4; ++r)
        Lg[(long)(row0 + r) * HIDD + col] = f2bf(acc[mi][ni][r] + bv);
    }
}

// ---------------- final LSTM pointwise (bf16 logits in) ----------------
__global__ void lstm_final(const unsigned short* __restrict__ logits,
                           const float* __restrict__ c_in, float* __restrict__ out) {
  const long GS = (long)B_DIM * HIDD;
  long i = (long)blockIdx.x * blockDim.x + threadIdx.x;   // over GS/8
  if (i >= (GS >> 3)) return;
  ushort8 u0 = *(const ushort8*)(logits + 8 * i);
  ushort8 u1 = *(const ushort8*)(logits + GS + 8 * i);
  ushort8 u2 = *(const ushort8*)(logits + 2 * GS + 8 * i);
  ushort8 u3 = *(const ushort8*)(logits + 3 * GS + 8 * i);
  f32x4 cv0 = *(const f32x4*)(c_in + 8 * i);
  f32x4 cv1 = *(const f32x4*)(c_in + 8 * i + 4);
  f32x4 h0, h1, c0, c1;
#pragma unroll
  for (int r = 0; r < 8; ++r) {
    float ig = 1.f / (1.f + __expf(-bf2f(u0[r])));
    float fg = 1.f / (1.f + __expf(-bf2f(u1[r])));
    float og = 1.f / (1.f + __expf(-bf2f(u2[r])));
    float gg = tanhf(bf2f(u3[r]));
    float cv = (r < 4) ? cv0[r] : cv1[r - 4];
    float c = fg * cv + ig * gg;
    float hh = og * tanhf(c);
    if (r < 4) { h0[r] = hh; c0[r] = c; } else { h1[r - 4] = hh; c1[r - 4] = c; }
  }
  *(f32x4*)(out + 8 * i) = h0;
  *(f32x4*)(out + 8 * i + 4) = h1;
  *(f32x4*)(out + GS + 8 * i) = c0;
  *(f32x4*)(out + GS + 8 * i + 4) = c1;
}

// ---------------- launch ----------------
extern "C" void kernel_launch(void* const* d_in, const int* in_sizes, int n_in,
                              void* d_out, int out_size, void* d_ws, size_t ws_size,
                              hipStream_t stream) {
  const float* v  = (const float*)d_in[0];
  const float* s  = (const float*)d_in[1];
  const float* x  = (const float*)d_in[2];
  const float* h  = (const float*)d_in[3];
  const float* c  = (const float*)d_in[4];
  const float* Wa = (const float*)d_in[5];
  const float* Wb = (const float*)d_in[6];
  const float* Wc = (const float*)d_in[7];
  const float* Ua = (const float*)d_in[8];
  const float* Ub = (const float*)d_in[9];
  const float* Uc = (const float*)d_in[10];
  const float* Ca = (const float*)d_in[11];
  const float* Cb = (const float*)d_in[12];
  const float* Cc = (const float*)d_in[13];
  const float* bb = (const float*)d_in[14];
  float* out = (float*)d_out;

  char* ws = (char*)d_ws;
  size_t off = 0;
  auto alloc = [&](size_t bytes) {
    char* p = ws + off;
    off = (off + bytes + 255) & ~(size_t)255;
    return p;
  };
  unsigned short* vb    = (unsigned short*)alloc((size_t)B_DIM * NFEATS * 2);
  unsigned short* sb    = (unsigned short*)alloc((size_t)B_DIM * NTAGSP * 2);
  unsigned short* xb    = (unsigned short*)alloc((size_t)B_DIM * RIN * 2);
  unsigned short* hb    = (unsigned short*)alloc((size_t)B_DIM * RHID * 2);
  unsigned short* WaT   = (unsigned short*)alloc((size_t)4 * 512 * 512 * 2);
  unsigned short* UaT   = (unsigned short*)alloc((size_t)4 * 512 * 512 * 2);
  unsigned short* CaT   = (unsigned short*)alloc((size_t)4 * 512 * NFEATS * 2);
  unsigned short* WcatT = (unsigned short*)alloc((size_t)4 * 512 * KCAT * 2);
  unsigned short* SBT   = (unsigned short*)alloc((size_t)3 * 2048 * NTAGSP * 2);   // [Cb|Wb|Ub]^T
  unsigned short* TSb   = (unsigned short*)alloc((size_t)3 * B_DIM * 2048 * 2);    // s-branch products
  unsigned short* Pbuf  = (unsigned short*)alloc((size_t)4 * B_DIM * KCAT * 2);
  unsigned short* Lg    = (unsigned short*)TSb;  // alias: TS dead once gemm_bil completes

  // 1) merged prep: activation converts + weight transposes (one dispatch)
  TP tp;
  tp.d[0] = { Wa, WaT,                  512, 512,  0,    0  };
  tp.d[1] = { Wb, SBT + 2048 * 320,     300, 320,  0,    8  };
  tp.d[2] = { Ua, UaT,                  512, 512,  0,    13 };
  tp.d[3] = { Ub, SBT + 2 * 2048 * 320, 300, 320,  0,    21 };
  tp.d[4] = { Ca, CaT,                 2048, 2048, 0,    26 };
  tp.d[5] = { Cb, SBT,                  300, 320,  0,    58 };
  tp.d[6] = { Wc, WcatT,                512, 1536, 0,    63 };
  tp.d[7] = { Cc, WcatT,                512, 1536, 512,  71 };
  tp.d[8] = { Uc, WcatT,                512, 1536, 1024, 79 };
  prep_all<<<dim3(2048 + 87 * 8 * 4), 256, 0, stream>>>(tp, v, x, h, s, vb, xb, hb, sb);

  // 2) GEMMs (triple-A 1-barrier cores; dynamic LDS 160KB / 112KB)
  hipFuncSetAttribute((const void*)gemm_ts,  hipFuncAttributeMaxDynamicSharedMemorySize, 163840);
  hipFuncSetAttribute((const void*)gemm_bil, hipFuncAttributeMaxDynamicSharedMemorySize, 163840);
  hipFuncSetAttribute((const void*)gemm_lg,  hipFuncAttributeMaxDynamicSharedMemorySize, 114688);

  gemm_ts<<<dim3(16, 24), 512, 163840, stream>>>(sb, SBT, TSb);
  gemm_bil<<<dim3(384), 512, 163840, stream>>>(vb, xb, hb, CaT, WaT, UaT, TSb, Pbuf);
  gemm_lg<<<dim3(256), 512, 114688, stream>>>(Pbuf, WcatT, bb, Lg);

  // 3) LSTM pointwise
  lstm_final<<<(B_DIM * HIDD / 8 + 255) / 256, 256, 0, stream>>>(Lg, c, out);
}

// Round 17
// 173.039 us; speedup vs baseline: 1.0170x; 1.0170x over previous
//
#include <hip/hip_runtime.h>
#include <hip/hip_bf16.h>
#include <stdint.h>

// Problem dims
#define B_DIM 4096
#define NFEATS 2048
#define NTAGS 300
#define NTAGSP 320
#define RIN 512
#define RHID 512
#define HIDD 512
#define KCAT 1536

typedef __attribute__((ext_vector_type(8))) short short8;
typedef __attribute__((ext_vector_type(8))) unsigned short ushort8;
typedef __attribute__((ext_vector_type(4))) float f32x4;

typedef __attribute__((address_space(3))) unsigned int lds_u32_t;
typedef __attribute__((address_space(1))) const unsigned int glb_u32_t;

__device__ __forceinline__ unsigned short f2bf(float f) {
  union { float f; unsigned u; } x; x.f = f;
  unsigned r = (x.u + 0x7fffu + ((x.u >> 16) & 1u)) >> 16;
  return (unsigned short)r;
}
__device__ __forceinline__ float bf2f(unsigned short u) {
  union { unsigned u; float f; } x; x.u = ((unsigned)u) << 16;
  return x.f;
}

__device__ __forceinline__ void gl2lds16(const void* g, void* l) {
  __builtin_amdgcn_global_load_lds((glb_u32_t*)g, (lds_u32_t*)l, 16, 0, 0);
}

__device__ __forceinline__ void sbar() {
  asm volatile("" ::: "memory");
  __builtin_amdgcn_s_barrier();
  asm volatile("" ::: "memory");
}
#define CB()       asm volatile("" ::: "memory")            // pin memory-op groups
#define SCHEDB()   __builtin_amdgcn_sched_barrier(0)        // pin non-memory ops (MFMA)
#define VMCNT4()   asm volatile("s_waitcnt vmcnt(4)" ::: "memory")
#define VMCNT2()   asm volatile("s_waitcnt vmcnt(2)" ::: "memory")
#define VMCNT0()   asm volatile("s_waitcnt vmcnt(0)" ::: "memory")
#define LGKMCNT0() asm volatile("s_waitcnt lgkmcnt(0)" ::: "memory")

// ---------------- merged prep: activation convert + weight transpose ----------------
struct TD { const float* src; unsigned short* dst; int K; int dstLd; int dstOff; int kx0; };
struct TP { TD d[9]; };

__global__ void prep_all(TP tp,
                         const float* __restrict__ v, const float* __restrict__ x,
                         const float* __restrict__ h, const float* __restrict__ s,
                         unsigned short* __restrict__ vb, unsigned short* __restrict__ xb,
                         unsigned short* __restrict__ hb, unsigned short* __restrict__ sb) {
  __shared__ float t[64][65];
  int bid = blockIdx.x;
  if (bid < 2048) {
    int seg = bid >> 9;
    int inner = bid & 511;
    const float* src; unsigned short* dst; int sc, dc;
    if (seg == 0)      { src = v; dst = vb; sc = NFEATS; dc = NFEATS; }
    else if (seg == 1) { src = x; dst = xb; sc = RIN;    dc = RIN; }
    else if (seg == 2) { src = h; dst = hb; sc = RHID;   dc = RHID; }
    else               { src = s; dst = sb; sc = NTAGS;  dc = NTAGSP; }
    int cpr = dc >> 3;
    long nch = (long)B_DIM * cpr;
    for (long i = (long)inner * blockDim.x + threadIdx.x; i < nch;
         i += (long)512 * blockDim.x) {
      int r = (int)(i / cpr);
      int c0 = (int)(i - (long)r * cpr) << 3;
      const float* sp = src + (long)r * sc + c0;
      ushort8 o;
#pragma unroll
      for (int j = 0; j < 8; ++j) {
        float f = (c0 + j < sc) ? sp[j] : 0.f;
        o[j] = f2bf(f);
      }
      *(ushort8*)(dst + (i << 3)) = o;
    }
  } else {
    int tb = bid - 2048;                 // 0..2783 = 87*8*4 - 1
    int bz = tb / (87 * 8);
    int rem = tb - bz * (87 * 8);
    int by = rem / 87;
    int bx = rem - by * 87;
    int m = 0;
#pragma unroll
    for (int i = 1; i < 9; ++i)
      if (bx >= tp.d[i].kx0) m = i;
    TD td = tp.d[m];
    const float* sp = td.src + (long)bz * td.K * 512;
    unsigned short* d = td.dst + (long)bz * 512 * td.dstLd;
    int k0 = (bx - td.kx0) * 64, n0 = by * 64;
    int tx = threadIdx.x & 63, ty = threadIdx.x >> 6;   // ty 0..3
#pragma unroll
    for (int p = 0; p < 16; ++p) {
      int kr = p * 4 + ty;
      int k = k0 + kr;
      t[kr][tx] = (k < td.K) ? sp[(long)k * 512 + n0 + tx] : 0.f;
    }
    __syncthreads();
#pragma unroll
    for (int p = 0; p < 16; ++p) {
      int nr = p * 4 + ty;
      d[(long)(n0 + nr) * td.dstLd + td.dstOff + k0 + tx] = f2bf(t[tx][nr]);
    }
  }
}

// ================= (64*MFR)x256 GEMM core, 2 barriers per K-tile =================
// Measured-best core (round 8, frozen). Schedule-bound at ~43% of the 16x16
// MFMA ceiling; falsified levers: balance (r6/7), epilogue vectorization
// (r12/13), triple-buffer single-barrier (r16), HBM (r11). Working levers
// already applied: 2-barrier interval (r8), T2 swizzle, counted vmcnt,
// setprio, XCD-chunked grids (r11).

__device__ __forceinline__ void stage_half(const unsigned short* mat, int ld,
                                           int gRow0, int k0, char* ldsHalf,
                                           int rl0, int scb, int dstoff) {
  const char* s0 = (const char*)(mat + (long)(gRow0 + rl0) * ld + k0) + scb;
  const char* s1 = (const char*)(mat + (long)(gRow0 + 64 + rl0) * ld + k0) + scb;
  gl2lds16(s0, ldsHalf + dstoff);
  gl2lds16(s1, ldsHalf + 8192 + dstoff);
}

template<int MFR>
__device__ __forceinline__ void mfma_q(f32x4 (&acc)[2 * MFR][4], int mb, int nb,
                                       const short8 (&af)[MFR][2], const short8 (&bf)[2][2]) {
  __builtin_amdgcn_s_setprio(1);
#pragma unroll
  for (int m = 0; m < MFR; ++m)
#pragma unroll
    for (int n = 0; n < 2; ++n)
#pragma unroll
      for (int kk = 0; kk < 2; ++kk)
        acc[mb + m][nb + n] =
            __builtin_amdgcn_mfma_f32_16x16x32_bf16(af[m][kk], bf[n][kk], acc[mb + m][nb + n], 0, 0, 0);
  __builtin_amdgcn_s_setprio(0);
}

template<int MFR>
__device__ __forceinline__ void gemm8_core(const unsigned short* __restrict__ A, int lda,
                                           const unsigned short* __restrict__ Bm, int ldb,
                                           int nt, int rowBase, int colBase,
                                           char* smem, int tid, f32x4 (&acc)[2 * MFR][4]) {
  constexpr int ATILE = 8192 * MFR;     // bytes per A K-tile (64*MFR rows x 128B)
  char* Ab0 = smem;                      // A dbuf: 2*ATILE
  char* Bb0 = smem + 2 * ATILE;          // B dbuf: 2*32KB
  int l = tid & 63, w = tid >> 6;
  int wr = w >> 2, wc = w & 3;
  int lr = l & 15, lg = l >> 4;
  int LA = lr * 128 + ((lg * 16) ^ ((lr & 7) << 4));   // swizzled lane read base
  int rl0 = tid >> 3;
  int scb = ((tid & 7) << 4) ^ ((rl0 & 7) << 4);       // inverse-swizzled src col
  int dstoff = (tid & ~63) << 4;                       // wave-uniform LDS base

#pragma unroll
  for (int mi = 0; mi < 2 * MFR; ++mi)
#pragma unroll
    for (int ni = 0; ni < 4; ++ni)
#pragma unroll
      for (int r = 0; r < 4; ++r) acc[mi][ni][r] = 0.f;

  // prologue: tile0 A+B -> buf0; tile1 A -> buf1.
  stage_half(A, lda, rowBase, 0, Ab0, rl0, scb, dstoff);
  if constexpr (MFR == 4) stage_half(A, lda, rowBase + 128, 0, Ab0 + ATILE / 2, rl0, scb, dstoff);
  stage_half(Bm, ldb, colBase, 0, Bb0, rl0, scb, dstoff);
  stage_half(Bm, ldb, colBase + 128, 0, Bb0 + 16384, rl0, scb, dstoff);
  if (nt > 1) {
    stage_half(A, lda, rowBase, 64, Ab0 + ATILE, rl0, scb, dstoff);
    if constexpr (MFR == 4) stage_half(A, lda, rowBase + 128, 64, Ab0 + ATILE + ATILE / 2, rl0, scb, dstoff);
    if constexpr (MFR == 4) { VMCNT4(); } else { VMCNT2(); }
  } else {
    VMCNT0();
  }
  sbar();

  for (int g = 0; g < nt; ++g) {
    int cur = g & 1;
    char* Ab = Ab0 + cur * ATILE + wr * (ATILE / 2);
    char* Bb = Bb0 + cur * 32768 + wc * 8192;
    char* BbN = Bb0 + (cur ^ 1) * 32768;
    short8 a0[MFR][2], a1[MFR][2], b0[2][2], b1[2][2];

    // ---- interval I: all reads + B staging + 3 MFMA quadrants ----
#pragma unroll
    for (int m = 0; m < MFR; ++m) {
      a0[m][0] = *(const short8*)(Ab + m * 2048 + LA);
      a0[m][1] = *(const short8*)(Ab + m * 2048 + (LA ^ 64));
    }
    CB();
#pragma unroll
    for (int n = 0; n < 2; ++n) {
      b0[n][0] = *(const short8*)(Bb + n * 2048 + LA);
      b0[n][1] = *(const short8*)(Bb + n * 2048 + (LA ^ 64));
    }
    CB();
    if (g + 1 < nt) stage_half(Bm, ldb, colBase, (g + 1) * 64, BbN, rl0, scb, dstoff);
#pragma unroll
    for (int n = 0; n < 2; ++n) {
      b1[n][0] = *(const short8*)(Bb + 4096 + n * 2048 + LA);
      b1[n][1] = *(const short8*)(Bb + 4096 + n * 2048 + (LA ^ 64));
    }
    CB();
    if (g + 1 < nt) stage_half(Bm, ldb, colBase + 128, (g + 1) * 64, BbN + 16384, rl0, scb, dstoff);
#pragma unroll
    for (int m = 0; m < MFR; ++m) {
      a1[m][0] = *(const short8*)(Ab + ATILE / 4 + m * 2048 + LA);
      a1[m][1] = *(const short8*)(Ab + ATILE / 4 + m * 2048 + (LA ^ 64));
    }
    CB();
    mfma_q<MFR>(acc, 0, 0, a0, b0);       // compiler inserts precise lgkmcnt waits
    mfma_q<MFR>(acc, 0, 2, a0, b1);
    mfma_q<MFR>(acc, MFR, 2, a1, b1);

    LGKMCNT0();                            // all this wave's LDS reads drained
    SCHEDB();
    sbar();                                // B1: every wave drained -> A[cur] writable

    if (g + 2 < nt) {
      stage_half(A, lda, rowBase, (g + 2) * 64, Ab0 + cur * ATILE, rl0, scb, dstoff);
      if constexpr (MFR == 4)
        stage_half(A, lda, rowBase + 128, (g + 2) * 64, Ab0 + cur * ATILE + ATILE / 2, rl0, scb, dstoff);
    }
    mfma_q<MFR>(acc, MFR, 0, a1, b0);

    if (g + 2 < nt) {
      if constexpr (MFR == 4) { VMCNT4(); } else { VMCNT2(); }
    } else if (g + 1 < nt) {
      VMCNT0();
    }
    SCHEDB();
    sbar();                                // B2: next tile's B landed
  }
}

// ---------------- GEMM kernels ----------------

// TS = s @ [Cb|Wb|Ub]^T  -> TS[3][4096][2048] bf16  (N=6144, K=320)
__global__ __launch_bounds__(512, 2) void gemm_ts(const unsigned short* __restrict__ sb,
                                                  const unsigned short* __restrict__ SBT,
                                                  unsigned short* __restrict__ TS) {
  extern __shared__ char smem[];
  int tid = threadIdx.x;
  int rowBase = blockIdx.x * 256, colBase = blockIdx.y * 256;
  f32x4 acc[8][4];
  gemm8_core<4>(sb, NTAGSP, SBT, NTAGSP, 5, rowBase, colBase, smem, tid, acc);

  int l = tid & 63, w = tid >> 6, wr = w >> 2, wc = w & 3, lr = l & 15, lg = l >> 4;
  int branch = colBase >> 11;
  unsigned short* TSb = TS + (long)branch * B_DIM * 2048;
#pragma unroll
  for (int mi = 0; mi < 8; ++mi)
#pragma unroll
    for (int ni = 0; ni < 4; ++ni) {
      int colg = (colBase & 2047) + wc * 64 + ni * 16 + lr;
      int row0 = rowBase + wr * 128 + mi * 16 + lg * 4;
#pragma unroll
      for (int r = 0; r < 4; ++r)
        TSb[(long)(row0 + r) * 2048 + colg] = f2bf(acc[mi][ni][r]);
    }
}

// P = (A1 @ B1^T) * TS. All blocks MFR=4 (256^2), 1-D grid, heavy z0 first.
// XCD-chunked remap: XCD (bid%8) owns a 4x4 tile chunk (FETCH 129->74MB, r11).
__global__ __launch_bounds__(512, 2) void gemm_bil(
    const unsigned short* __restrict__ vb, const unsigned short* __restrict__ xb,
    const unsigned short* __restrict__ hb,
    const unsigned short* __restrict__ CaT, const unsigned short* __restrict__ WaT,
    const unsigned short* __restrict__ UaT,
    const unsigned short* __restrict__ TS, unsigned short* __restrict__ P) {
  extern __shared__ char smem[];
  int tid = threadIdx.x;
  int bid = blockIdx.x;
  int z, nt, coff, K1;
  const unsigned short *A1, *B1;
  int t;
  if (bid < 128) {
    z = 0; A1 = vb; B1 = CaT; K1 = NFEATS; nt = 32; coff = 512; t = bid;
  } else {
    t = bid - 128;
    z = 1 + (t >> 7); t &= 127;
    A1 = (z == 1) ? xb : hb;
    B1 = (z == 1) ? WaT : UaT;
    K1 = RIN; nt = 8; coff = (z == 1) ? 0 : 1024;
  }
  // XCD-chunked 4x4 mapping (t in 0..127; XCD = bid%8 = t%8 since 128%8==0)
  int gx = t & 7, k = t >> 3;
  int rowBase = ((gx >> 1) * 4 + (k >> 2)) * 256;   // 16 row tiles
  int colBase = ((gx & 1) * 4 + (k & 3)) * 256;     // 8 col tiles

  f32x4 acc[8][4];
  gemm8_core<4>(A1, K1, B1, K1, nt, rowBase, colBase, smem, tid, acc);

  int l = tid & 63, w = tid >> 6, wr = w >> 2, wc = w & 3, lr = l & 15, lg = l >> 4;
  const unsigned short* TSz = TS + (long)z * B_DIM * 2048;
#pragma unroll
  for (int mi = 0; mi < 8; ++mi)
#pragma unroll
    for (int ni = 0; ni < 4; ++ni) {
      int colg = colBase + wc * 64 + ni * 16 + lr;
      int gate = colg >> 9;
      int col = coff + (colg & 511);
      int row0 = rowBase + wr * 128 + mi * 16 + lg * 4;
      unsigned short* Pg = P + (long)gate * B_DIM * KCAT;
#pragma unroll
      for (int r = 0; r < 4; ++r) {
        float ts = bf2f(TSz[(long)(row0 + r) * 2048 + colg]);
        Pg[(long)(row0 + r) * KCAT + col] = f2bf(acc[mi][ni][r] * ts);
      }
    }
}

// logits[g] = P[g] @ Wcat[g]^T + b[g]  (128x256 tiles, MFR=2; bf16 output)
// 1-D grid 256; XCD (bid%8) owns one (gate, row-half): Wg fetched once per XCD.
__global__ __launch_bounds__(512, 2) void gemm_lg(const unsigned short* __restrict__ P,
                                                  const unsigned short* __restrict__ WcT,
                                                  const float* __restrict__ bias,
                                                  unsigned short* __restrict__ logits) {
  extern __shared__ char smem[];
  int tid = threadIdx.x;
  int bid = blockIdx.x;
  int gx = bid & 7, k = bid >> 3;           // gx = XCD
  int gate = gx >> 1;
  int rowBase = ((gx & 1) * 16 + (k >> 1)) * 128;   // 32 row tiles of 128
  int colBase = (k & 1) * 256;                      // 2 col tiles
  const unsigned short* Pg = P + (long)gate * B_DIM * KCAT;
  const unsigned short* Wg = WcT + (long)gate * 512 * KCAT;
  f32x4 acc[4][4];
  gemm8_core<2>(Pg, KCAT, Wg, KCAT, KCAT / 64, rowBase, colBase, smem, tid, acc);

  int l = tid & 63, w = tid >> 6, wr = w >> 2, wc = w & 3, lr = l & 15, lg = l >> 4;
  unsigned short* Lg = logits + (long)gate * B_DIM * HIDD;
  const float* bg = bias + gate * HIDD;
#pragma unroll
  for (int mi = 0; mi < 4; ++mi)
#pragma unroll
    for (int ni = 0; ni < 4; ++ni) {
      int col = colBase + wc * 64 + ni * 16 + lr;
      float bv = bg[col];
      int row0 = rowBase + wr * 64 + mi * 16 + lg * 4;
#pragma unroll
      for (int r = 0; r < 4; ++r)
        Lg[(long)(row0 + r) * HIDD + col] = f2bf(acc[mi][ni][r] + bv);
    }
}

// ---------------- final LSTM pointwise (bf16 logits in) ----------------
__global__ void lstm_final(const unsigned short* __restrict__ logits,
                           const float* __restrict__ c_in, float* __restrict__ out) {
  const long GS = (long)B_DIM * HIDD;
  long i = (long)blockIdx.x * blockDim.x + threadIdx.x;   // over GS/8
  if (i >= (GS >> 3)) return;
  ushort8 u0 = *(const ushort8*)(logits + 8 * i);
  ushort8 u1 = *(const ushort8*)(logits + GS + 8 * i);
  ushort8 u2 = *(const ushort8*)(logits + 2 * GS + 8 * i);
  ushort8 u3 = *(const ushort8*)(logits + 3 * GS + 8 * i);
  f32x4 cv0 = *(const f32x4*)(c_in + 8 * i);
  f32x4 cv1 = *(const f32x4*)(c_in + 8 * i + 4);
  f32x4 h0, h1, c0, c1;
#pragma unroll
  for (int r = 0; r < 8; ++r) {
    float ig = 1.f / (1.f + __expf(-bf2f(u0[r])));
    float fg = 1.f / (1.f + __expf(-bf2f(u1[r])));
    float og = 1.f / (1.f + __expf(-bf2f(u2[r])));
    float gg = tanhf(bf2f(u3[r]));
    float cv = (r < 4) ? cv0[r] : cv1[r - 4];
    float c = fg * cv + ig * gg;
    float hh = og * tanhf(c);
    if (r < 4) { h0[r] = hh; c0[r] = c; } else { h1[r - 4] = hh; c1[r - 4] = c; }
  }
  *(f32x4*)(out + 8 * i) = h0;
  *(f32x4*)(out + 8 * i + 4) = h1;
  *(f32x4*)(out + GS + 8 * i) = c0;
  *(f32x4*)(out + GS + 8 * i + 4) = c1;
}

// ---------------- launch ----------------
extern "C" void kernel_launch(void* const* d_in, const int* in_sizes, int n_in,
                              void* d_out, int out_size, void* d_ws, size_t ws_size,
                              hipStream_t stream) {
  const float* v  = (const float*)d_in[0];
  const float* s  = (const float*)d_in[1];
  const float* x  = (const float*)d_in[2];
  const float* h  = (const float*)d_in[3];
  const float* c  = (const float*)d_in[4];
  const float* Wa = (const float*)d_in[5];
  const float* Wb = (const float*)d_in[6];
  const float* Wc = (const float*)d_in[7];
  const float* Ua = (const float*)d_in[8];
  const float* Ub = (const float*)d_in[9];
  const float* Uc = (const float*)d_in[10];
  const float* Ca = (const float*)d_in[11];
  const float* Cb = (const float*)d_in[12];
  const float* Cc = (const float*)d_in[13];
  const float* bb = (const float*)d_in[14];
  float* out = (float*)d_out;

  char* ws = (char*)d_ws;
  size_t off = 0;
  auto alloc = [&](size_t bytes) {
    char* p = ws + off;
    off = (off + bytes + 255) & ~(size_t)255;
    return p;
  };
  unsigned short* vb    = (unsigned short*)alloc((size_t)B_DIM * NFEATS * 2);
  unsigned short* sb    = (unsigned short*)alloc((size_t)B_DIM * NTAGSP * 2);
  unsigned short* xb    = (unsigned short*)alloc((size_t)B_DIM * RIN * 2);
  unsigned short* hb    = (unsigned short*)alloc((size_t)B_DIM * RHID * 2);
  unsigned short* WaT   = (unsigned short*)alloc((size_t)4 * 512 * 512 * 2);
  unsigned short* UaT   = (unsigned short*)alloc((size_t)4 * 512 * 512 * 2);
  unsigned short* CaT   = (unsigned short*)alloc((size_t)4 * 512 * NFEATS * 2);
  unsigned short* WcatT = (unsigned short*)alloc((size_t)4 * 512 * KCAT * 2);
  unsigned short* SBT   = (unsigned short*)alloc((size_t)3 * 2048 * NTAGSP * 2);   // [Cb|Wb|Ub]^T
  unsigned short* TSb   = (unsigned short*)alloc((size_t)3 * B_DIM * 2048 * 2);    // s-branch products
  unsigned short* Pbuf  = (unsigned short*)alloc((size_t)4 * B_DIM * KCAT * 2);
  unsigned short* Lg    = (unsigned short*)TSb;  // alias: TS dead once gemm_bil completes

  // 1) merged prep: activation converts + weight transposes (one dispatch)
  TP tp;
  tp.d[0] = { Wa, WaT,                  512, 512,  0,    0  };
  tp.d[1] = { Wb, SBT + 2048 * 320,     300, 320,  0,    8  };
  tp.d[2] = { Ua, UaT,                  512, 512,  0,    13 };
  tp.d[3] = { Ub, SBT + 2 * 2048 * 320, 300, 320,  0,    21 };
  tp.d[4] = { Ca, CaT,                 2048, 2048, 0,    26 };
  tp.d[5] = { Cb, SBT,                  300, 320,  0,    58 };
  tp.d[6] = { Wc, WcatT,                512, 1536, 0,    63 };
  tp.d[7] = { Cc, WcatT,                512, 1536, 512,  71 };
  tp.d[8] = { Uc, WcatT,                512, 1536, 1024, 79 };
  prep_all<<<dim3(2048 + 87 * 8 * 4), 256, 0, stream>>>(tp, v, x, h, s, vb, xb, hb, sb);

  // 2) GEMMs (2-barrier-per-tile cores; dynamic LDS)
  hipFuncSetAttribute((const void*)gemm_ts,  hipFuncAttributeMaxDynamicSharedMemorySize, 131072);
  hipFuncSetAttribute((const void*)gemm_bil, hipFuncAttributeMaxDynamicSharedMemorySize, 131072);
  hipFuncSetAttribute((const void*)gemm_lg,  hipFuncAttributeMaxDynamicSharedMemorySize, 98304);

  gemm_ts<<<dim3(16, 24), 512, 131072, stream>>>(sb, SBT, TSb);
  gemm_bil<<<dim3(384), 512, 131072, stream>>>(vb, xb, hb, CaT, WaT, UaT, TSb, Pbuf);
  gemm_lg<<<dim3(256), 512, 98304, stream>>>(Pbuf, WcatT, bb, Lg);

  // 3) LSTM pointwise
  lstm_final<<<(B_DIM * HIDD / 8 + 255) / 256, 256, 0, stream>>>(Lg, c, out);
}